// Round 2
// baseline (99.582 us; speedup 1.0000x reference)
//
#include <hip/hip_runtime.h>

// Maj3: out[n,a] = 3 * sum_{G=0..191} clip( sum_{U=0..2} p[n][U*192+G] * w[a][U*192+G], -1, 1 )
//   p = flattened 3x3 patch of x, layout j = c*9 + u*3 + v (c-major), padded -1.
//   U = j/192, G = j%192.  w in {-1,+1} exact floats -> use fma directly.
//
// Structure (R1): lane = position. Block = 64 positions (2 w-rows x 32 h),
// 16 channels, 4 waves = 2 ch-groups x 2 G-halves. Raw x tile in LDS
// [4w][64c][35h] (35.8KB, conflict-free); per (triple,U,d) the tile offset
// is a compile-time immediate off one rolling base (chunk-of-3 triples keeps
// the mod-3 decode static). Weights read as raw +/-1.0 floats (wave-uniform,
// L2-resident) -> s = fma(x1,w1, fma(x2,w2, x3*w3)); clip via fmed3.

#define TW 2240  // 64 * 35 words per w-plane

typedef float f4 __attribute__((ext_vector_type(4)));

__device__ __forceinline__ float clip1(float s) {
    return __builtin_amdgcn_fmed3f(s, -1.0f, 1.0f);
}

// Process 32 triples t = T0 .. T0+31 (G = 3*T0 .. 3*T0+95) for 8 channels.
// tile word addr for (t,U,d):  Bb + ci*35 + u*TW + Kc*35 + d   where
//   u  = (t+U) % 3  = (T0+k+64U) % 3          (compile-time per k,U)
//   Kc = (T0+k+64U-u)/3                        (compile-time per k,U)
//   t  = T0 + 3*ci + k
template <int T0>
__device__ __forceinline__ void g_half(const float* __restrict__ tile,
                                       const float* __restrict__ w,
                                       int a0, int Bb, float acc[8]) {
    int Bw = Bb;
#pragma unroll 1
    for (int ci = 0; ci < 10; ++ci) {
        float xv[3][3][3];
#pragma unroll
        for (int k = 0; k < 3; ++k)
#pragma unroll
            for (int U = 0; U < 3; ++U) {
                const int u   = (T0 + k + 64 * U) % 3;
                const int Kc  = (T0 + k + 64 * U - u) / 3;
                const int off = u * TW + Kc * 35;
#pragma unroll
                for (int d = 0; d < 3; ++d)
                    xv[k][U][d] = tile[Bw + off + d];
            }
#pragma unroll
        for (int ch = 0; ch < 8; ++ch) {
            const float* wp = w + (a0 + ch) * 576 + 3 * T0 + 9 * ci;
            float wf[3][9];
#pragma unroll
            for (int U = 0; U < 3; ++U)
                __builtin_memcpy(&wf[U][0], wp + U * 192, 36);
            float a = 0.0f;
#pragma unroll
            for (int k = 0; k < 3; ++k)
#pragma unroll
                for (int d = 0; d < 3; ++d) {
                    float s = fmaf(xv[k][0][d], wf[0][3 * k + d],
                              fmaf(xv[k][1][d], wf[1][3 * k + d],
                                   xv[k][2][d] * wf[2][3 * k + d]));
                    a += clip1(s);
                }
            acc[ch] += a;
        }
        Bw += 35;
    }
    // epilogue: triples t = T0+30, T0+31 (ci = 10, k = 0..1)
    {
        float xv[2][3][3];
#pragma unroll
        for (int k = 0; k < 2; ++k)
#pragma unroll
            for (int U = 0; U < 3; ++U) {
                const int u   = (T0 + k + 64 * U) % 3;
                const int Kc  = (T0 + k + 64 * U - u) / 3;
                const int off = u * TW + Kc * 35;
#pragma unroll
                for (int d = 0; d < 3; ++d)
                    xv[k][U][d] = tile[Bw + off + d];
            }
#pragma unroll
        for (int ch = 0; ch < 8; ++ch) {
            const float* wp = w + (a0 + ch) * 576 + 3 * T0 + 90;
            float wf[3][6];
#pragma unroll
            for (int U = 0; U < 3; ++U)
                __builtin_memcpy(&wf[U][0], wp + U * 192, 24);
            float a = 0.0f;
#pragma unroll
            for (int k = 0; k < 2; ++k)
#pragma unroll
                for (int d = 0; d < 3; ++d) {
                    float s = fmaf(xv[k][0][d], wf[0][3 * k + d],
                              fmaf(xv[k][1][d], wf[1][3 * k + d],
                                   xv[k][2][d] * wf[2][3 * k + d]));
                    a += clip1(s);
                }
            acc[ch] += a;
        }
    }
}

__global__ __launch_bounds__(256, 2) void maj3_kernel(
        const float* __restrict__ x, const float* __restrict__ w,
        float* __restrict__ out) {
    __shared__ float tile[4 * TW];     // 35,840 B : [wi:4][c:64][hh:35]
    __shared__ float red[2][8][64];    //  4,096 B : G-half reduction

    const int tid  = threadIdx.x;
    const int lane = tid & 63;
    const int wid  = tid >> 6;
    const int blk  = blockIdx.x;          // 512 = 128 sets * 4 ch-splits
    const int set  = blk >> 2;            // (b_img, w-pair)
    const int a0b  = (blk & 3) << 4;      // block channel base (16 ch)
    const int bimg = set >> 4;
    const int w0   = (set & 15) << 1;

    // ---- stage raw tile: tile[wi][c][hh] = x[bimg][w0+wi-1][hh-1][c] or -1
    // wave wid handles plane wi = wid; lane = c (global reads coalesced,
    // LDS write stride 35 words -> bank 3c, conflict-free).
    {
        const int wx  = w0 + wid - 1;
        const bool ok = (unsigned)wx < 32u;
        const float* xp = x + ((bimg * 32 + wx) * 32) * 64 + lane;
#pragma unroll 1
        for (int hh = 0; hh < 34; ++hh) {
            const int hx = hh - 1;
            float v = -1.0f;
            if (ok && (unsigned)hx < 32u) v = xp[hx * 64];
            tile[wid * TW + lane * 35 + hh] = v;
        }
    }
    __syncthreads();

    const int chgrp = wid >> 1;           // which 8-channel group
    const int ghalf = wid & 1;            // which 96-G half
    const int a0    = a0b + chgrp * 8;
    const int Bb    = (lane >> 5) * TW + (lane & 31);  // wl*2240 + hl

    float acc[8] = {0, 0, 0, 0, 0, 0, 0, 0};
    if (ghalf == 0) g_half<0>(tile, w, a0, Bb, acc);
    else            g_half<32>(tile, w, a0, Bb, acc);

    if (ghalf == 1) {
#pragma unroll
        for (int k = 0; k < 8; ++k) red[chgrp][k][lane] = acc[k];
    }
    __syncthreads();

    if (ghalf == 0) {
        const int wl = lane >> 5, hl = lane & 31;
        float* op = out + ((bimg * 32 + w0 + wl) * 32 + hl) * 64 + a0;
        f4 o0, o1;
#pragma unroll
        for (int k = 0; k < 4; ++k)
            o0[k] = 3.0f * (acc[k] + red[chgrp][k][lane]);
#pragma unroll
        for (int k = 0; k < 4; ++k)
            o1[k] = 3.0f * (acc[4 + k] + red[chgrp][4 + k][lane]);
        *(f4*)(op)     = o0;   // a0 multiple of 8 -> 32B aligned
        *(f4*)(op + 4) = o1;
    }
}

extern "C" void kernel_launch(void* const* d_in, const int* in_sizes, int n_in,
                              void* d_out, int out_size, void* d_ws, size_t ws_size,
                              hipStream_t stream) {
    const float* x = (const float*)d_in[0];   // (8,32,32,64) f32
    const float* w = (const float*)d_in[1];   // (64,576) f32, exact +/-1.0
    float* out = (float*)d_out;               // (8,32,32,64) f32
    maj3_kernel<<<512, 256, 0, stream>>>(x, w, out);
}

// Round 3
// 72.738 us; speedup vs baseline: 1.3691x; 1.3691x over previous
//
#include <hip/hip_runtime.h>

// Maj3: out[n,a] = 3 * sum_{G=0..191} clip( sum_{U=0..2} p[n][U*192+G]*w[a][U*192+G], -1, 1 )
//   p flat j = c*9+u*3+v (c-major 3x3 patch, pad -1), U=j/192, G=j%192.
//
// R2: fix latency-boundness seen in R1 counters (VALUBusy 22%, Occ 20%):
//  - grid 1024 (8ch-splits) -> 4 blocks/CU, 16 waves/CU
//  - weight loads made wave-uniform via readfirstlane -> scalar K$ (s_load),
//    off the VALU/VMEM critical path; weights are exact +/-1.0 floats -> fma
//  - staging loads fully unrolled (34 in flight)
// Wave = 4 channels x 96 G (one G-half); lane = position (2 w-rows x 32 h).

#define TW 2240  // 64 c * 35 h-stride words per w-plane

typedef float f4 __attribute__((ext_vector_type(4)));

__device__ __forceinline__ float clip1(float s) {
    return __builtin_amdgcn_fmed3f(s, -1.0f, 1.0f);
}

// triples t = T0..T0+31 (G = 3*T0..3*T0+95) for 4 channels a0u..a0u+3.
// tile word addr for (t=T0+3ci+k, U, d): Bb + ci*35 + u*TW + Kc*35 + d,
//   u = (T0+k+64U)%3, Kc = (T0+k+64U-u)/3   (compile-time per k,U)
template <int T0>
__device__ __forceinline__ void g_half(const float* __restrict__ tile,
                                       const float* __restrict__ w,
                                       int a0u, int Bb, float acc[4]) {
    int Bw = Bb;
#pragma unroll 1
    for (int ci = 0; ci < 10; ++ci) {
        float xv[3][3][3];
#pragma unroll
        for (int k = 0; k < 3; ++k)
#pragma unroll
            for (int U = 0; U < 3; ++U) {
                const int u   = (T0 + k + 64 * U) % 3;
                const int Kc  = (T0 + k + 64 * U - u) / 3;
                const int off = u * TW + Kc * 35;
#pragma unroll
                for (int d = 0; d < 3; ++d)
                    xv[k][U][d] = tile[Bw + off + d];
            }
#pragma unroll
        for (int ch = 0; ch < 4; ++ch) {
            // uniform address -> scalar loads into SGPRs
            const float* wp = w + (a0u + ch) * 576 + 3 * T0 + 9 * ci;
            float wf[3][9];
#pragma unroll
            for (int U = 0; U < 3; ++U)
#pragma unroll
                for (int q = 0; q < 9; ++q) wf[U][q] = wp[U * 192 + q];
            float a = acc[ch];
#pragma unroll
            for (int k = 0; k < 3; ++k)
#pragma unroll
                for (int d = 0; d < 3; ++d) {
                    float s = fmaf(xv[k][0][d], wf[0][3 * k + d],
                              fmaf(xv[k][1][d], wf[1][3 * k + d],
                                   xv[k][2][d] * wf[2][3 * k + d]));
                    a += clip1(s);
                }
            acc[ch] = a;
        }
        Bw += 35;
    }
    // epilogue: triples T0+30, T0+31
    {
        float xv[2][3][3];
#pragma unroll
        for (int k = 0; k < 2; ++k)
#pragma unroll
            for (int U = 0; U < 3; ++U) {
                const int u   = (T0 + k + 64 * U) % 3;
                const int Kc  = (T0 + k + 64 * U - u) / 3;
                const int off = u * TW + Kc * 35;
#pragma unroll
                for (int d = 0; d < 3; ++d)
                    xv[k][U][d] = tile[Bw + off + d];
            }
#pragma unroll
        for (int ch = 0; ch < 4; ++ch) {
            const float* wp = w + (a0u + ch) * 576 + 3 * T0 + 90;
            float wf[3][6];
#pragma unroll
            for (int U = 0; U < 3; ++U)
#pragma unroll
                for (int q = 0; q < 6; ++q) wf[U][q] = wp[U * 192 + q];
            float a = acc[ch];
#pragma unroll
            for (int k = 0; k < 2; ++k)
#pragma unroll
                for (int d = 0; d < 3; ++d) {
                    float s = fmaf(xv[k][0][d], wf[0][3 * k + d],
                              fmaf(xv[k][1][d], wf[1][3 * k + d],
                                   xv[k][2][d] * wf[2][3 * k + d]));
                    a += clip1(s);
                }
            acc[ch] = a;
        }
    }
}

__global__ __launch_bounds__(256, 4) void maj3_kernel(
        const float* __restrict__ x, const float* __restrict__ w,
        float* __restrict__ out) {
    __shared__ float tile[4 * TW];     // 35,840 B : [wi:4][c:64][hh:35]
    __shared__ float red[2][4][64];    //  2,048 B : G-half partial sums

    const int tid  = threadIdx.x;
    const int lane = tid & 63;
    const int wid  = tid >> 6;
    const int blk  = blockIdx.x;          // 1024 = 128 sets * 8 ch-splits
    const int set  = blk >> 3;
    const int a0b  = (blk & 7) << 3;      // block channel base (8 ch)
    const int bimg = set >> 4;
    const int w0   = (set & 15) << 1;

    // ---- stage tile[wi][c][hh] = x[bimg][w0+wi-1][hh-1][c] or -1 ----------
    // wave wid -> plane wi=wid; lane = c. Fully unrolled: 32 loads in flight.
    {
        const int wx  = w0 + wid - 1;
        const bool ok = (unsigned)wx < 32u;
        const float* xp = x + ((bimg * 32 + wx) * 32) * 64 + lane;
        float vs[34];
#pragma unroll
        for (int hh = 0; hh < 34; ++hh) {
            const int hx = hh - 1;
            vs[hh] = -1.0f;
            if (ok && (unsigned)hx < 32u) vs[hh] = xp[hx * 64];
        }
#pragma unroll
        for (int hh = 0; hh < 34; ++hh)
            tile[wid * TW + lane * 35 + hh] = vs[hh];
    }
    __syncthreads();

    const int chgrp = (wid >> 1) & 1;     // which 4-channel group
    const int ghalf = wid & 1;            // which 96-G half
    const int a0u   = __builtin_amdgcn_readfirstlane(a0b + chgrp * 4);
    const int Bb    = (lane >> 5) * TW + (lane & 31);  // wl*TW + hl

    float acc[4] = {0.f, 0.f, 0.f, 0.f};
    if (ghalf == 0) g_half<0>(tile, w, a0u, Bb, acc);
    else            g_half<32>(tile, w, a0u, Bb, acc);

    if (ghalf == 1) {
#pragma unroll
        for (int k = 0; k < 4; ++k) red[chgrp][k][lane] = acc[k];
    }
    __syncthreads();

    if (ghalf == 0) {
        const int wl = lane >> 5, hl = lane & 31;
        float* op = out + ((bimg * 32 + w0 + wl) * 32 + hl) * 64 + a0u;
        f4 o;
#pragma unroll
        for (int k = 0; k < 4; ++k)
            o[k] = 3.0f * (acc[k] + red[chgrp][k][lane]);
        *(f4*)op = o;   // a0u multiple of 4 -> 16B aligned
    }
}

extern "C" void kernel_launch(void* const* d_in, const int* in_sizes, int n_in,
                              void* d_out, int out_size, void* d_ws, size_t ws_size,
                              hipStream_t stream) {
    const float* x = (const float*)d_in[0];   // (8,32,32,64) f32
    const float* w = (const float*)d_in[1];   // (64,576) f32, exact +/-1.0
    float* out = (float*)d_out;               // (8,32,32,64) f32
    maj3_kernel<<<1024, 256, 0, stream>>>(x, w, out);
}

// Round 4
// 72.596 us; speedup vs baseline: 1.3717x; 1.0020x over previous
//
#include <hip/hip_runtime.h>

// Maj3: out[n,a] = 3 * sum_{G=0..191} clip( sum_{U=0..2} p[n][U*192+G]*w[a][U*192+G], -1, 1 )
//   p flat j = c*9+u*3+v (c-major 3x3 patch, pad -1), U=j/192, G=j%192.
//
// R3: LDS-pipe was the structural bottleneck (R2: 16 waves/CU x 288 ds_read
// x 5.8cyc = 26.7k cyc/CU > VALU 15.4k). Wave shape 4ch x 96G -> 8ch x 48G:
// each xv triple-read now feeds 8 channels -> LDS/CU halves to ~13.4k, VALU
// becomes the cap. Block = 4 waves = 4 G-quarters x same 8 ch; reduction
// reuses tile LDS after a sync (no extra LDS -> still 4 blocks/CU).

#define TW 2240  // 64 c * 35 h-stride words per w-plane

typedef float f4 __attribute__((ext_vector_type(4)));

__device__ __forceinline__ float clip1(float s) {
    return __builtin_amdgcn_fmed3f(s, -1.0f, 1.0f);
}

// One G-quarter: triples t = T0..T0+15 (G = 3*T0..3*T0+47) for 8 channels.
// tile word addr for (t=T0+3ci+k, U, d): Bb + ci*35 + u*TW + Kc*35 + d,
//   u = (T0+k+64U)%3, Kc = (T0+k+64U-u)/3   (compile-time per k,U)
template <int T0>
__device__ __forceinline__ void g_quarter(const float* __restrict__ tile,
                                          const float* __restrict__ w,
                                          int a0, int Bb, float acc[8]) {
    int Bw = Bb;
#pragma unroll 1
    for (int ci = 0; ci < 5; ++ci) {
        float xv[3][3][3];
#pragma unroll
        for (int k = 0; k < 3; ++k)
#pragma unroll
            for (int U = 0; U < 3; ++U) {
                const int u   = (T0 + k + 64 * U) % 3;
                const int Kc  = (T0 + k + 64 * U - u) / 3;
                const int off = u * TW + Kc * 35;
#pragma unroll
                for (int d = 0; d < 3; ++d)
                    xv[k][U][d] = tile[Bw + off + d];
            }
#pragma unroll
        for (int ch = 0; ch < 8; ++ch) {
            // blockIdx-derived address -> scalar s_load into SGPRs
            const float* wp = w + (a0 + ch) * 576 + 3 * T0 + 9 * ci;
            float wf[3][9];
#pragma unroll
            for (int U = 0; U < 3; ++U)
#pragma unroll
                for (int q = 0; q < 9; ++q) wf[U][q] = wp[U * 192 + q];
            float a = acc[ch];
#pragma unroll
            for (int k = 0; k < 3; ++k)
#pragma unroll
                for (int d = 0; d < 3; ++d) {
                    float s = fmaf(xv[k][0][d], wf[0][3 * k + d],
                              fmaf(xv[k][1][d], wf[1][3 * k + d],
                                   xv[k][2][d] * wf[2][3 * k + d]));
                    a += clip1(s);
                }
            acc[ch] = a;
        }
        Bw += 35;
    }
    // epilogue: single triple t = T0+15 (ci = 5, k = 0)
    {
        float xv[3][3];
#pragma unroll
        for (int U = 0; U < 3; ++U) {
            const int u   = (T0 + 64 * U) % 3;
            const int Kc  = (T0 + 64 * U - u) / 3;
            const int off = u * TW + Kc * 35;
#pragma unroll
            for (int d = 0; d < 3; ++d)
                xv[U][d] = tile[Bw + off + d];
        }
#pragma unroll
        for (int ch = 0; ch < 8; ++ch) {
            const float* wp = w + (a0 + ch) * 576 + 3 * T0 + 45;
            float wf[3][3];
#pragma unroll
            for (int U = 0; U < 3; ++U)
#pragma unroll
                for (int q = 0; q < 3; ++q) wf[U][q] = wp[U * 192 + q];
            float a = acc[ch];
#pragma unroll
            for (int d = 0; d < 3; ++d) {
                float s = fmaf(xv[0][d], wf[0][d],
                          fmaf(xv[1][d], wf[1][d],
                               xv[2][d] * wf[2][d]));
                a += clip1(s);
            }
            acc[ch] = a;
        }
    }
}

__global__ __launch_bounds__(256, 4) void maj3_kernel(
        const float* __restrict__ x, const float* __restrict__ w,
        float* __restrict__ out) {
    __shared__ float tile[4 * TW];     // 35,840 B : [wi:4][c:64][hh:35]
    // reduction scratch reuses tile[0..1535] after all waves finish reading

    const int tid  = threadIdx.x;
    const int lane = tid & 63;
    const int wid  = tid >> 6;            // = G-quarter index
    const int blk  = blockIdx.x;          // 1024 = 128 sets * 8 ch-splits
    const int set  = blk >> 3;
    const int a0   = (blk & 7) << 3;      // block channel base (8 ch)
    const int bimg = set >> 4;
    const int w0   = (set & 15) << 1;

    // ---- stage tile[wi][c][hh] = x[bimg][w0+wi-1][hh-1][c] or -1 ----------
    // wave wid -> plane wi=wid; lane = c. Fully unrolled: 32 loads in flight.
    {
        const int wx  = w0 + wid - 1;
        const bool ok = (unsigned)wx < 32u;
        const float* xp = x + ((bimg * 32 + wx) * 32) * 64 + lane;
        float vs[34];
#pragma unroll
        for (int hh = 0; hh < 34; ++hh) {
            const int hx = hh - 1;
            vs[hh] = -1.0f;
            if (ok && (unsigned)hx < 32u) vs[hh] = xp[hx * 64];
        }
#pragma unroll
        for (int hh = 0; hh < 34; ++hh)
            tile[wid * TW + lane * 35 + hh] = vs[hh];
    }
    __syncthreads();

    const int Bb = (lane >> 5) * TW + (lane & 31);  // wl*TW + hl

    float acc[8] = {0, 0, 0, 0, 0, 0, 0, 0};
    if      (wid == 0) g_quarter<0>(tile, w, a0, Bb, acc);
    else if (wid == 1) g_quarter<16>(tile, w, a0, Bb, acc);
    else if (wid == 2) g_quarter<32>(tile, w, a0, Bb, acc);
    else               g_quarter<48>(tile, w, a0, Bb, acc);

    __syncthreads();   // all reads of tile done -> safe to reuse as scratch
    if (wid != 0) {
#pragma unroll
        for (int k = 0; k < 8; ++k)
            tile[((wid - 1) * 8 + k) * 64 + lane] = acc[k];
    }
    __syncthreads();

    if (wid == 0) {
        const int wl = lane >> 5, hl = lane & 31;
        float* op = out + ((bimg * 32 + w0 + wl) * 32 + hl) * 64 + a0;
        f4 o0, o1;
#pragma unroll
        for (int k = 0; k < 8; ++k) {
            float v = acc[k] + tile[(0 * 8 + k) * 64 + lane]
                             + tile[(1 * 8 + k) * 64 + lane]
                             + tile[(2 * 8 + k) * 64 + lane];
            if (k < 4) o0[k] = 3.0f * v;
            else       o1[k - 4] = 3.0f * v;
        }
        *(f4*)(op)     = o0;   // a0 multiple of 8 -> 32B aligned
        *(f4*)(op + 4) = o1;
    }
}

extern "C" void kernel_launch(void* const* d_in, const int* in_sizes, int n_in,
                              void* d_out, int out_size, void* d_ws, size_t ws_size,
                              hipStream_t stream) {
    const float* x = (const float*)d_in[0];   // (8,32,32,64) f32
    const float* w = (const float*)d_in[1];   // (64,576) f32, exact +/-1.0
    float* out = (float*)d_out;               // (8,32,32,64) f32
    maj3_kernel<<<1024, 256, 0, stream>>>(x, w, out);
}